// Round 8
// baseline (326.877 us; speedup 1.0000x reference)
//
#include <hip/hip_runtime.h>
#include <hip/hip_bf16.h>
#include <stdint.h>

namespace {

constexpr int MTOT = 8192;   // 4 * 2048 rows of x
constexpr int NTOT = 4096;   // OUT_DIM
constexpr int KTOT = 4096;   // IN_DIM

constexpr int BM = 256, BN = 128, BK = 32;
constexpr int NT = KTOT / BK;     // 128 K-tiles

typedef __attribute__((ext_vector_type(8))) short bf16x8;
typedef __attribute__((ext_vector_type(4))) float f32x4;

__device__ inline unsigned short to_bf16(float f) {
    union { float f; uint32_t u; } v; v.f = f;
    return (unsigned short)((v.u + 0x7FFFu + ((v.u >> 16) & 1u)) >> 16);
}

// ---- Kernel 1: fp32 -> bf16 convert of x (8 elems / thread) ----
__global__ __launch_bounds__(256) void convert_x_kernel(const float* __restrict__ x,
                                                        unsigned short* __restrict__ xb) {
    int idx = blockIdx.x * 256 + threadIdx.x;
    const f32x4* xv = reinterpret_cast<const f32x4*>(x);
    f32x4 v0 = xv[2 * idx];
    f32x4 v1 = xv[2 * idx + 1];
    union { bf16x8 v; unsigned short s[8]; } o;
    o.s[0] = to_bf16(v0.x); o.s[1] = to_bf16(v0.y);
    o.s[2] = to_bf16(v0.z); o.s[3] = to_bf16(v0.w);
    o.s[4] = to_bf16(v1.x); o.s[5] = to_bf16(v1.y);
    o.s[6] = to_bf16(v1.z); o.s[7] = to_bf16(v1.w);
    reinterpret_cast<bf16x8*>(xb)[idx] = o.v;
}

// ---- Kernel 2: W[o][i] = sum_b a[b][o/512][i/512] * s[b][o%512][i%512], bf16 out ----
__global__ __launch_bounds__(256) void gen_w_kernel(const float* __restrict__ a,
                                                    const float* __restrict__ s,
                                                    unsigned short* __restrict__ w) {
    int idx = blockIdx.x * 256 + threadIdx.x;   // 4096 * 512 threads
    int o  = idx >> 9;
    int i8 = idx & 511;
    int i0 = i8 * 8;
    int obig = o >> 9, orow = o & 511;
    int ibig = i0 >> 9, icol = i0 & 511;

    float acc[8];
#pragma unroll
    for (int j = 0; j < 8; ++j) acc[j] = 0.f;

#pragma unroll
    for (int b = 0; b < 8; ++b) {
        float av = a[b * 64 + obig * 8 + ibig];
        const f32x4* sv = reinterpret_cast<const f32x4*>(s + b * 512 * 512 + orow * 512 + icol);
        f32x4 s0 = sv[0], s1 = sv[1];
        acc[0] += av * s0.x; acc[1] += av * s0.y; acc[2] += av * s0.z; acc[3] += av * s0.w;
        acc[4] += av * s1.x; acc[5] += av * s1.y; acc[6] += av * s1.z; acc[7] += av * s1.w;
    }
    union { bf16x8 v; unsigned short q[8]; } ov;
#pragma unroll
    for (int j = 0; j < 8; ++j) ov.q[j] = to_bf16(acc[j]);
    reinterpret_cast<bf16x8*>(w)[idx] = ov.v;
}

// ---- Kernel 3: C[m,n] = sum_k A[m,k] * B[n,k] ----
// 256x128 block tile, 4 waves (2Mx2N, wave tile 128x64), BK=32, ring-3 LDS
// (72 KiB -> 2 blocks/CU: each SIMD hosts 2 waves from DIFFERENT blocks,
// never barrier-synced -> LDS-read phase of one overlaps MFMA of the other).
// Counted vmcnt(6) gate, prefetch distance 2 tiles, XOR swizzle, setprio.
__global__ __launch_bounds__(256, 2)
void gemm_bt_kernel(const unsigned short* __restrict__ A,
                    const unsigned short* __restrict__ B,
                    float* __restrict__ C) {
    __shared__ __align__(16) unsigned short As[3][BM][BK];   // 48 KiB
    __shared__ __align__(16) unsigned short Bs[3][BN][BK];   // 24 KiB

    // XCD-aware bijective swizzle: 1024 blocks, 8 XCDs, 128 blocks/XCD
    int bid = blockIdx.x;
    int swz = (bid & 7) * 128 + (bid >> 3);
    int bm = swz >> 5;                 // 0..31  (8192/256)
    int bn = swz & 31;                 // 0..31  (4096/128)

    int tid  = threadIdx.x;
    int wid  = tid >> 6;               // 0..3
    int lane = tid & 63;
    int wm = wid >> 1, wn = wid & 1;   // wave owns 128x64 of C

    // staging geometry (pre-swizzled global source, linear LDS dest)
    int srow  = lane >> 2;                              // 0..15
    int sslot = (lane & 3) ^ ((srow >> 1) & 3);
    const unsigned short* ag = A + (size_t)(bm * BM + wid * 64 + srow) * KTOT + sslot * 8;
    const unsigned short* bg = B + (size_t)(bn * BN + wid * 32 + srow) * KTOT + sslot * 8;

    // fragment-read geometry (same XOR on read side); rslot lane-constant
    int rl    = lane & 15;
    int rslot = (lane >> 4) ^ ((rl >> 1) & 3);

    f32x4 acc[8][4];
#pragma unroll
    for (int m = 0; m < 8; ++m)
#pragma unroll
        for (int n = 0; n < 4; ++n) acc[m][n] = (f32x4)0.f;

    // per tile: wave stages 4 A-gloads (rows wid*64+g*16) + 2 B-gloads = 6 loads
    auto STAGE = [&](int s, int k0) {
#pragma unroll
        for (int g = 0; g < 4; ++g)
            __builtin_amdgcn_global_load_lds(
                (const __attribute__((address_space(1))) void*)(ag + (size_t)g * 16 * KTOT + k0),
                (__attribute__((address_space(3))) void*)&As[s][wid * 64 + g * 16][0], 16, 0, 0);
#pragma unroll
        for (int g = 0; g < 2; ++g)
            __builtin_amdgcn_global_load_lds(
                (const __attribute__((address_space(1))) void*)(bg + (size_t)g * 16 * KTOT + k0),
                (__attribute__((address_space(3))) void*)&Bs[s][wid * 32 + g * 16][0], 16, 0, 0);
    };

    auto COMPUTE = [&](int s) {
        bf16x8 fa[8], fb[4];
#pragma unroll
        for (int m = 0; m < 8; ++m)
            fa[m] = *reinterpret_cast<const bf16x8*>(&As[s][wm * 128 + m * 16 + rl][rslot * 8]);
#pragma unroll
        for (int n = 0; n < 4; ++n)
            fb[n] = *reinterpret_cast<const bf16x8*>(&Bs[s][wn * 64 + n * 16 + rl][rslot * 8]);
        asm volatile("s_waitcnt lgkmcnt(0)" ::: "memory");
        __builtin_amdgcn_sched_barrier(0);
        __builtin_amdgcn_s_setprio(1);
#pragma unroll
        for (int m = 0; m < 8; ++m)
#pragma unroll
            for (int n = 0; n < 4; ++n)
                acc[m][n] = __builtin_amdgcn_mfma_f32_16x16x32_bf16(fa[m], fb[n], acc[m][n], 0, 0, 0);
        __builtin_amdgcn_s_setprio(0);
    };

    // ---- prologue: stage tiles 0,1 (12 loads); force tile 0 resident ----
    STAGE(0, 0);
    STAGE(1, BK);
    asm volatile("s_waitcnt vmcnt(6)" ::: "memory");
    __builtin_amdgcn_s_barrier();

    // ---- main loop: tiles 0..125 staged (stages t+2, through tile 127) ----
    for (int tb = 0; tb < NT - 2; tb += 3) {
#pragma unroll
        for (int u = 0; u < 3; ++u) {
            const int t = tb + u;
            STAGE((u + 2) % 3, (t + 2) * BK);   // issue next-next tile first
            COMPUTE(u);                          // ds_read + MFMA on tile t
            // gate: force tile t+1 resident (6 of t+2's loads stay in flight)
            asm volatile("s_waitcnt vmcnt(6)" ::: "memory");
            __builtin_amdgcn_s_barrier();
        }
    }
    // ---- tail: tiles 126 (slot 0) and 127 (slot 1), no staging ----
    COMPUTE(0);
    asm volatile("s_waitcnt vmcnt(0)" ::: "memory");
    __builtin_amdgcn_s_barrier();
    COMPUTE(1);

    // ---- C write: per 16x16 frag, col = lane&15, row = (lane>>4)*4 + j ----
    int crow0 = bm * BM + wm * 128 + (lane >> 4) * 4;
    int ccol0 = bn * BN + wn * 64 + (lane & 15);
#pragma unroll
    for (int m = 0; m < 8; ++m)
#pragma unroll
        for (int n = 0; n < 4; ++n)
#pragma unroll
            for (int j = 0; j < 4; ++j) {
                size_t r = (size_t)(crow0 + m * 16 + j);
                size_t c = (size_t)(ccol0 + n * 16);
                C[r * NTOT + c] = acc[m][n][j];
            }
}

} // anonymous namespace

extern "C" void kernel_launch(void* const* d_in, const int* in_sizes, int n_in,
                              void* d_out, int out_size, void* d_ws, size_t ws_size,
                              hipStream_t stream) {
    const float* x = (const float*)d_in[0];   // (4,2048,4096) f32
    const float* a = (const float*)d_in[1];   // (8,8,8) f32
    const float* s = (const float*)d_in[2];   // (8,512,512) f32
    float* out = (float*)d_out;               // (4,2048,4096) f32

    unsigned short* xb = (unsigned short*)d_ws;                    // 64 MiB bf16 x
    unsigned short* wb = xb + (size_t)MTOT * KTOT;                 // 32 MiB bf16 W

    convert_x_kernel<<<(MTOT * KTOT / 8) / 256, 256, 0, stream>>>(x, xb);
    gen_w_kernel<<<(NTOT * KTOT / 8) / 256, 256, 0, stream>>>(a, s, wb);
    gemm_bt_kernel<<<(MTOT / BM) * (NTOT / BN), 256, 0, stream>>>(xb, wb, out);
}

// Round 9
// 323.882 us; speedup vs baseline: 1.0092x; 1.0092x over previous
//
#include <hip/hip_runtime.h>
#include <hip/hip_bf16.h>
#include <stdint.h>

namespace {

constexpr int MTOT = 8192;   // 4 * 2048 rows of x
constexpr int NTOT = 4096;   // OUT_DIM
constexpr int KTOT = 4096;   // IN_DIM

typedef __attribute__((ext_vector_type(8))) short bf16x8;
typedef __attribute__((ext_vector_type(4))) float f32x4;

__device__ inline unsigned short to_bf16(float f) {
    union { float f; uint32_t u; } v; v.f = f;
    return (unsigned short)((v.u + 0x7FFFu + ((v.u >> 16) & 1u)) >> 16);
}

// ---- Kernel 1: fp32 -> bf16 convert of x (8 elems / thread) ----
__global__ __launch_bounds__(256) void convert_x_kernel(const float* __restrict__ x,
                                                        unsigned short* __restrict__ xb) {
    int idx = blockIdx.x * 256 + threadIdx.x;
    const f32x4* xv = reinterpret_cast<const f32x4*>(x);
    f32x4 v0 = xv[2 * idx];
    f32x4 v1 = xv[2 * idx + 1];
    union { bf16x8 v; unsigned short s[8]; } o;
    o.s[0] = to_bf16(v0.x); o.s[1] = to_bf16(v0.y);
    o.s[2] = to_bf16(v0.z); o.s[3] = to_bf16(v0.w);
    o.s[4] = to_bf16(v1.x); o.s[5] = to_bf16(v1.y);
    o.s[6] = to_bf16(v1.z); o.s[7] = to_bf16(v1.w);
    reinterpret_cast<bf16x8*>(xb)[idx] = o.v;
}

// ---- Kernel 2: W[o][i] = sum_b a[b][o/512][i/512] * s[b][o%512][i%512], bf16 out ----
__global__ __launch_bounds__(256) void gen_w_kernel(const float* __restrict__ a,
                                                    const float* __restrict__ s,
                                                    unsigned short* __restrict__ w) {
    int idx = blockIdx.x * 256 + threadIdx.x;   // 4096 * 512 threads
    int o  = idx >> 9;
    int i8 = idx & 511;
    int i0 = i8 * 8;
    int obig = o >> 9, orow = o & 511;
    int ibig = i0 >> 9, icol = i0 & 511;

    float acc[8];
#pragma unroll
    for (int j = 0; j < 8; ++j) acc[j] = 0.f;

#pragma unroll
    for (int b = 0; b < 8; ++b) {
        float av = a[b * 64 + obig * 8 + ibig];
        const f32x4* sv = reinterpret_cast<const f32x4*>(s + b * 512 * 512 + orow * 512 + icol);
        f32x4 s0 = sv[0], s1 = sv[1];
        acc[0] += av * s0.x; acc[1] += av * s0.y; acc[2] += av * s0.z; acc[3] += av * s0.w;
        acc[4] += av * s1.x; acc[5] += av * s1.y; acc[6] += av * s1.z; acc[7] += av * s1.w;
    }
    union { bf16x8 v; unsigned short q[8]; } ov;
#pragma unroll
    for (int j = 0; j < 8; ++j) ov.q[j] = to_bf16(acc[j]);
    reinterpret_cast<bf16x8*>(w)[idx] = ov.v;
}

// ---- Kernel 3: C[m,n] = sum_k A[m,k] * B[n,k] ----
// m201-style 8-phase schedule, derived waits. 256x256 tile, K-tile=64,
// iter = 2 K-tiles (buf0 = even tile, phases 1-4; buf1 = odd, phases 5-8).
// Wave (2M x 4N) ownership INTERLEAVED: m-frag f at block-row (f&3)*32+wm*16
// (+128 if f>=4), n-frag g at block-col (g&1)*64+wn*16 (+128 if g>=2), so
// phase quadrant (m-half, n-half) reads exactly one 128-row half of A/B.
// One half-tile staged per phase (rotation after each half's last read);
// vmcnt(4) at phases 4 & 8 only. All stage/read/drain hazards table-verified.
__global__ __launch_bounds__(512, 2)
void gemm_bt_kernel(const unsigned short* __restrict__ A,
                    const unsigned short* __restrict__ B,
                    float* __restrict__ C) {
    __shared__ __align__(16) unsigned short As[2][2][128][64];   // [buf][half][row][col]
    __shared__ __align__(16) unsigned short Bs[2][2][128][64];

    // XCD-aware bijective swizzle: 512 blocks, 8 XCDs, 64 blocks/XCD
    int bid = blockIdx.x;
    int swz = (bid & 7) * 64 + (bid >> 3);
    int bm = swz >> 4;                 // 32 m-tiles
    int bn = swz & 15;                 // 16 n-tiles

    int tid  = threadIdx.x;
    int wid  = tid >> 6;               // 0..7
    int lane = tid & 63;
    int wm = wid >> 2, wn = wid & 3;

    int r8 = lane >> 3;                // 0..7  (staging row within 8-row group)
    int su = (lane & 7) ^ r8;          // pre-swizzled source 16B-unit
    int rl = lane & 15;
    int kq = lane >> 4;                // 0..3  (k-quarter)
    int qx = rl & 7;                   // read-side XOR key

    const size_t K = (size_t)KTOT;
    const unsigned short* Abase = A + (size_t)(bm * 256 + wid * 16 + r8) * K + su * 8;
    const unsigned short* Bbase = B + (size_t)(bn * 256 + wid * 16 + r8) * K + su * 8;

    // stage one 128x64 half-tile: 2 gloads/wave (rows wid*16+0..7, +8..15)
    auto SA = [&](int buf, int h, int tile) {
        const unsigned short* src = Abase + (size_t)(h * 128) * K + tile * 64;
        __builtin_amdgcn_global_load_lds(
            (const __attribute__((address_space(1))) void*)src,
            (__attribute__((address_space(3))) void*)&As[buf][h][wid * 16][0], 16, 0, 0);
        __builtin_amdgcn_global_load_lds(
            (const __attribute__((address_space(1))) void*)(src + 8 * K),
            (__attribute__((address_space(3))) void*)&As[buf][h][wid * 16 + 8][0], 16, 0, 0);
    };
    auto SB = [&](int buf, int h, int tile) {
        const unsigned short* src = Bbase + (size_t)(h * 128) * K + tile * 64;
        __builtin_amdgcn_global_load_lds(
            (const __attribute__((address_space(1))) void*)src,
            (__attribute__((address_space(3))) void*)&Bs[buf][h][wid * 16][0], 16, 0, 0);
        __builtin_amdgcn_global_load_lds(
            (const __attribute__((address_space(1))) void*)(src + 8 * K),
            (__attribute__((address_space(3))) void*)&Bs[buf][h][wid * 16 + 8][0], 16, 0, 0);
    };

    // fragment reads (XOR-swizzled): logical 16B-unit = ks*4+kq, phys = ^ (row&7)
    auto LA = [&](int buf, int f, int ks) -> bf16x8 {
        int rh = (f & 3) * 32 + wm * 16 + rl;
        int q  = (ks * 4 + kq) ^ qx;
        return *reinterpret_cast<const bf16x8*>(&As[buf][f >> 2][rh][q * 8]);
    };
    auto LB = [&](int buf, int g, int ks) -> bf16x8 {
        int rh = (g & 1) * 64 + wn * 16 + rl;
        int q  = (ks * 4 + kq) ^ qx;
        return *reinterpret_cast<const bf16x8*>(&Bs[buf][g >> 1][rh][q * 8]);
    };

    f32x4 acc[8][4];
#pragma unroll
    for (int m = 0; m < 8; ++m)
#pragma unroll
        for (int n = 0; n < 4; ++n) acc[m][n] = (f32x4)0.f;

    bf16x8 a[4][2], bL[2][2], bH[2][2];

    auto FENCE = [&]() {
        __builtin_amdgcn_s_barrier();
        asm volatile("s_waitcnt lgkmcnt(0)" ::: "memory");
        __builtin_amdgcn_sched_barrier(0);
    };
    auto MM = [&](bf16x8 (&af)[4][2], bf16x8 (&bf)[2][2], int f0, int g0) {
        __builtin_amdgcn_s_setprio(1);
#pragma unroll
        for (int i = 0; i < 4; ++i)
#pragma unroll
            for (int gi = 0; gi < 2; ++gi)
#pragma unroll
                for (int ks = 0; ks < 2; ++ks)
                    acc[f0 + i][g0 + gi] = __builtin_amdgcn_mfma_f32_16x16x32_bf16(
                        af[i][ks], bf[gi][ks], acc[f0 + i][g0 + gi], 0, 0, 0);
        __builtin_amdgcn_s_setprio(0);
        __builtin_amdgcn_s_barrier();
    };

    // ---- prologue: tile0 all 4 halves, tile1 h0-halves + B1h1 (14 gloads/wave) ----
    SA(0, 0, 0); SB(0, 0, 0); SB(0, 1, 0); SA(0, 1, 0);
    SA(1, 0, 1); SB(1, 0, 1); SB(1, 1, 1);
    asm volatile("s_waitcnt vmcnt(6)" ::: "memory");   // tile0 fully resident
    __builtin_amdgcn_s_barrier();

    // ---- main loop: 32 iters x (2 K64-tiles), 8 phases each ----
    for (int j = 0; j < 32; ++j) {
        const bool full = (j < 31);
        const int t2 = 2 * j + 2, t3 = 2 * j + 3;

        // PH1 (buf0, mh0 x nh0): read A0-lo (8) + B0-lo (4); stage buf1.A-h1 (tile 2j+1)
#pragma unroll
        for (int i = 0; i < 4; ++i) { a[i][0] = LA(0, i, 0); a[i][1] = LA(0, i, 1); }
#pragma unroll
        for (int gi = 0; gi < 2; ++gi) { bL[gi][0] = LB(0, gi, 0); bL[gi][1] = LB(0, gi, 1); }
        SA(1, 1, 2 * j + 1);
        FENCE(); MM(a, bL, 0, 0);

        // PH2 (mh0 x nh1): read B0-hi (4); stage buf0.A-h0 (tile 2j+2)
#pragma unroll
        for (int gi = 0; gi < 2; ++gi) { bH[gi][0] = LB(0, gi + 2, 0); bH[gi][1] = LB(0, gi + 2, 1); }
        if (full) SA(0, 0, t2);
        FENCE(); MM(a, bH, 0, 2);

        // PH3 (mh1 x nh0): read A0-hi (8); stage buf0.B-h0
#pragma unroll
        for (int i = 0; i < 4; ++i) { a[i][0] = LA(0, i + 4, 0); a[i][1] = LA(0, i + 4, 1); }
        if (full) SB(0, 0, t2);
        FENCE(); MM(a, bL, 4, 0);

        // PH4 (mh1 x nh1): no reads; stage buf0.B-h1; counted gate
        if (full) { SB(0, 1, t2); asm volatile("s_waitcnt vmcnt(4)" ::: "memory"); }
        else      {               asm volatile("s_waitcnt vmcnt(0)" ::: "memory"); }
        FENCE(); MM(a, bH, 4, 2);

        // PH5 (buf1, mh0 x nh0): read A1-lo + B1-lo; stage buf0.A-h1
#pragma unroll
        for (int i = 0; i < 4; ++i) { a[i][0] = LA(1, i, 0); a[i][1] = LA(1, i, 1); }
#pragma unroll
        for (int gi = 0; gi < 2; ++gi) { bL[gi][0] = LB(1, gi, 0); bL[gi][1] = LB(1, gi, 1); }
        if (full) SA(0, 1, t2);
        FENCE(); MM(a, bL, 0, 0);

        // PH6 (mh0 x nh1): read B1-hi; stage buf1.A-h0 (tile 2j+3)
#pragma unroll
        for (int gi = 0; gi < 2; ++gi) { bH[gi][0] = LB(1, gi + 2, 0); bH[gi][1] = LB(1, gi + 2, 1); }
        if (full) SA(1, 0, t3);
        FENCE(); MM(a, bH, 0, 2);

        // PH7 (mh1 x nh0): read A1-hi; stage buf1.B-h0
#pragma unroll
        for (int i = 0; i < 4; ++i) { a[i][0] = LA(1, i + 4, 0); a[i][1] = LA(1, i + 4, 1); }
        if (full) SB(1, 0, t3);
        FENCE(); MM(a, bL, 4, 0);

        // PH8 (mh1 x nh1): no reads; stage buf1.B-h1; counted gate
        if (full) { SB(1, 1, t3); asm volatile("s_waitcnt vmcnt(4)" ::: "memory"); }
        FENCE(); MM(a, bH, 4, 2);
    }

    // ---- C write: frag rows (f&3)*32+wm*16+(f>>2)*128 + (lane>>4)*4+jj,
    //               cols (g&1)*64+wn*16+(g>>1)*128 + (lane&15) ----
    int rq = (lane >> 4) * 4;
#pragma unroll
    for (int f = 0; f < 8; ++f)
#pragma unroll
        for (int g = 0; g < 4; ++g)
#pragma unroll
            for (int jj = 0; jj < 4; ++jj) {
                size_t r = (size_t)(bm * 256 + (f & 3) * 32 + wm * 16 + (f >> 2) * 128 + rq + jj);
                size_t c = (size_t)(bn * 256 + (g & 1) * 64 + wn * 16 + (g >> 1) * 128 + (lane & 15));
                C[r * NTOT + c] = acc[f][g][jj];
            }
}

} // anonymous namespace

extern "C" void kernel_launch(void* const* d_in, const int* in_sizes, int n_in,
                              void* d_out, int out_size, void* d_ws, size_t ws_size,
                              hipStream_t stream) {
    const float* x = (const float*)d_in[0];   // (4,2048,4096) f32
    const float* a = (const float*)d_in[1];   // (8,8,8) f32
    const float* s = (const float*)d_in[2];   // (8,512,512) f32
    float* out = (float*)d_out;               // (4,2048,4096) f32

    unsigned short* xb = (unsigned short*)d_ws;                    // 64 MiB bf16 x
    unsigned short* wb = xb + (size_t)MTOT * KTOT;                 // 32 MiB bf16 W

    convert_x_kernel<<<(MTOT * KTOT / 8) / 256, 256, 0, stream>>>(x, xb);
    gen_w_kernel<<<(NTOT * KTOT / 8) / 256, 256, 0, stream>>>(a, s, wb);
    gemm_bt_kernel<<<(MTOT / 256) * (NTOT / 256), 512, 0, stream>>>(xb, wb, out);
}